// Round 3
// baseline (2010.820 us; speedup 1.0000x reference)
//
#include <hip/hip_runtime.h>

#define NI 32
#define CI 128
#define HI 112
#define WI 112
#define OC 256
#define HO 110
#define WO 110

typedef float f32x4 __attribute__((ext_vector_type(4)));
typedef short s16x8 __attribute__((ext_vector_type(8)));

__device__ __forceinline__ ushort f2bf(float f) {
  union { float f; unsigned int u; } x; x.f = f;
  unsigned int r = x.u + 0x7FFFu + ((x.u >> 16) & 1u);
  return (ushort)(r >> 16);
}

// weight [oc][c][kh][kw] fp32 -> wp2 [kk][chalf][cc][oc][32ch] bf16
// (per (kk,chalf,cc): 256 oc x 32 ch, so one A-frag wave-load = contiguous 1 KB)
__global__ __launch_bounds__(256) void pack_w_kernel(const float* __restrict__ w,
                                                     ushort* __restrict__ wp) {
  int i = blockIdx.x * 256 + threadIdx.x;  // 294912
  int e = i & 7;
  int k8 = (i >> 3) & 3;
  int oc = (i >> 5) & 255;
  int cc = (i >> 13) & 1;
  int chalf = (i >> 14) & 1;
  int kk = i >> 15;  // 0..8
  int ch = chalf * 64 + cc * 32 + k8 * 8 + e;
  int kh = kk / 3, kw = kk - kh * 3;
  wp[i] = f2bf(w[((oc * CI + ch) * 3 + kh) * 3 + kw]);
}

// x [n][c][h][w] fp32 -> xn [n][chalf][h][w][64c] bf16
__global__ __launch_bounds__(256) void to_nhwc_kernel(const float* __restrict__ x,
                                                      ushort* __restrict__ xn) {
  __shared__ ushort lds[WI * CI];  // lds[w*128 + c], 28 KB
  int b = blockIdx.x;              // n*112 + h
  int n = b / HI;
  int h = b - n * HI;
  const float* xr = x + ((size_t)n * CI * HI) * WI + (size_t)h * WI;
  int t = threadIdx.x;
  for (int i = t; i < WI * CI; i += 256) {
    int w = i >> 7, c = i & 127;
    lds[i] = f2bf(xr[(size_t)c * (HI * WI) + w]);
  }
  __syncthreads();
  #pragma unroll
  for (int chalf = 0; chalf < 2; ++chalf) {
    uint4* dp = (uint4*)(xn + (((size_t)n * 2 + chalf) * HI + h) * (WI * 64));
    for (int i = t; i < (WI * 64) / 8; i += 256) {  // 896 chunks
      int w = i >> 3, cl8 = (i & 7) * 8;
      dp[i] = *(const uint4*)&lds[w * CI + chalf * 64 + cl8];
    }
  }
}

// Implicit GEMM, 16x16x32 MFMA, K split into 2 chunks of 64 ch so LDS = 57.6 KB
// -> 2 blocks/CU (4 waves/SIMD). Block = (n, 2 output rows) x 256 oc, 8 waves.
__global__ __launch_bounds__(512, 4) void conv_mfma_kernel(const ushort* __restrict__ xn,
                                                           const ushort* __restrict__ wp,
                                                           const float* __restrict__ bias,
                                                           float* __restrict__ out) {
  // 4 staged rows x 112 pix x 64 ch = 448 rows of 128 B (+2 pad rows) = 57600 B
  __shared__ ushort lds[450 * 64];
  const int bid = blockIdx.x;
  const int n = bid / 55;
  const int rp = bid - n * 55;
  const int oh0 = rp * 2;
  const int t = threadIdx.x;
  const int lane = t & 63;
  const int wid = t >> 6;
  const int lane15 = lane & 15;
  const int laneh = lane >> 4;
  const int ocq = wid & 3;
  const int ph = wid >> 2;
  const int oc0 = ocq * 64;
  char* ldsb = (char*)lds;

  f32x4 acc[4][7] = {};  // [mf: oc 16-frag][nf: ow 16-frag]

  #pragma unroll
  for (int chalf = 0; chalf < 2; ++chalf) {
    if (chalf) __syncthreads();  // protect LDS from prior chunk's readers
    // ---- stage 4 rows of this channel-half: linear LDS <- pre-swizzled global ----
    const char* gsb = (const char*)(xn + (((size_t)n * 2 + chalf) * HI + oh0) * (WI * 64));
    #pragma unroll
    for (int i = 0; i < 7; ++i) {
      int L = (i * 512 + t) * 16;            // 7*512*16 = 57344 B
      int go = L ^ (((L >> 7) & 7) << 4);    // swizzle 16B slots within 128B rows
      *(s16x8*)(ldsb + L) = *(const s16x8*)(gsb + go);
    }
    __syncthreads();

    // ---- compute: 9 taps x 2 K-chunks of 32 ----
    #pragma unroll
    for (int kh = 0; kh < 3; ++kh) {
      #pragma unroll
      for (int kw = 0; kw < 3; ++kw) {
        const int kk = kh * 3 + kw;
        const ushort* wb = wp + (size_t)(kk * 2 + chalf) * (2 * 256 * 32) +
                           (oc0 + lane15) * 32 + laneh * 8;
        s16x8 a[4][2];
        #pragma unroll
        for (int cc = 0; cc < 2; ++cc)
          #pragma unroll
          for (int mf = 0; mf < 4; ++mf)
            a[mf][cc] = *(const s16x8*)(wb + cc * (256 * 32) + mf * (16 * 32));
        #pragma unroll
        for (int cc = 0; cc < 2; ++cc) {
          s16x8 bfr[7];
          #pragma unroll
          for (int nf = 0; nf < 7; ++nf) {
            int R = (ph + kh) * 112 + nf * 16 + lane15 + kw;  // staged row index
            int addr = (R << 7) + (((laneh * 16) ^ ((R & 7) << 4)) ^ (cc << 6));
            bfr[nf] = *(const s16x8*)(ldsb + addr);
          }
          #pragma unroll
          for (int mf = 0; mf < 4; ++mf)
            #pragma unroll
            for (int nf = 0; nf < 7; ++nf)
              acc[mf][nf] = __builtin_amdgcn_mfma_f32_16x16x32_bf16(a[mf][cc], bfr[nf],
                                                                    acc[mf][nf], 0, 0, 0);
        }
      }
    }
  }

  // ---- epilogue: D col=lane15 -> ow, row=laneh*4+r -> oc ----
  const int oh = oh0 + ph;
  float* outb = out + ((size_t)n * OC) * (HO * WO) + (size_t)oh * WO;
  #pragma unroll
  for (int mf = 0; mf < 4; ++mf) {
    #pragma unroll
    for (int r = 0; r < 4; ++r) {
      const int oc = oc0 + mf * 16 + laneh * 4 + r;
      const float bv = bias[oc];
      float* op = outb + (size_t)oc * (HO * WO);
      #pragma unroll
      for (int nf = 0; nf < 7; ++nf) {
        int ow = nf * 16 + lane15;
        if (ow < WO) op[ow] = acc[mf][nf][r] + bv;
      }
    }
  }
}

// Correctness fallback if ws is too small for the packed bf16 buffers.
__global__ __launch_bounds__(256) void conv_naive_kernel(const float* __restrict__ x,
                                                         const float* __restrict__ w,
                                                         const float* __restrict__ bias,
                                                         float* __restrict__ out) {
  long i = (long)blockIdx.x * 256 + threadIdx.x;
  const long total = (long)NI * OC * HO * WO;
  if (i >= total) return;
  int ow = (int)(i % WO);
  long r1 = i / WO;
  int oh = (int)(r1 % HO);
  long r2 = r1 / HO;
  int oc = (int)(r2 % OC);
  int n = (int)(r2 / OC);
  float s = bias[oc];
  const float* xb = x + ((size_t)n * CI * HI) * WI;
  const float* wb = w + (size_t)oc * CI * 9;
  for (int c = 0; c < CI; ++c)
    for (int kh = 0; kh < 3; ++kh)
      for (int kw = 0; kw < 3; ++kw)
        s += xb[((size_t)c * HI + oh + kh) * WI + ow + kw] * wb[(c * 3 + kh) * 3 + kw];
  out[i] = s;
}

extern "C" void kernel_launch(void* const* d_in, const int* in_sizes, int n_in,
                              void* d_out, int out_size, void* d_ws, size_t ws_size,
                              hipStream_t stream) {
  const float* x = (const float*)d_in[0];
  const float* w = (const float*)d_in[1];
  const float* bias = (const float*)d_in[2];
  float* out = (float*)d_out;

  const size_t xn_elems = (size_t)NI * 2 * HI * WI * 64;  // 51,380,224
  const size_t wp_elems = (size_t)9 * 2 * 2 * 256 * 32;   // 294,912
  const size_t need = (xn_elems + wp_elems) * sizeof(ushort);

  if (ws_size >= need) {
    ushort* xnw = (ushort*)d_ws;
    ushort* wpw = xnw + xn_elems;
    hipLaunchKernelGGL(pack_w_kernel, dim3((unsigned)(wp_elems / 256)), dim3(256), 0, stream,
                       w, wpw);
    hipLaunchKernelGGL(to_nhwc_kernel, dim3(NI * HI), dim3(256), 0, stream, x, xnw);
    hipLaunchKernelGGL(conv_mfma_kernel, dim3(NI * 55), dim3(512), 0, stream, xnw, wpw, bias,
                       out);
  } else {
    long total = (long)NI * OC * HO * WO;
    hipLaunchKernelGGL(conv_naive_kernel, dim3((unsigned)((total + 255) / 256)), dim3(256), 0,
                       stream, x, w, bias, out);
  }
}

// Round 4
// 372.059 us; speedup vs baseline: 5.4046x; 5.4046x over previous
//
#include <hip/hip_runtime.h>

#define NI 32
#define CI 128
#define HI 112
#define WI 112
#define OC 256
#define HO 110
#define WO 110

typedef float f32x4 __attribute__((ext_vector_type(4)));
typedef short s16x8 __attribute__((ext_vector_type(8)));

typedef const unsigned int __attribute__((address_space(1))) gu32;
typedef unsigned int __attribute__((address_space(3))) lu32;

__device__ __forceinline__ ushort f2bf(float f) {
  union { float f; unsigned int u; } x; x.f = f;
  unsigned int r = x.u + 0x7FFFu + ((x.u >> 16) & 1u);
  return (ushort)(r >> 16);
}

// weight [oc][c][kh][kw] fp32 -> wp [kk][chalf][cc][oc][32ch] bf16
__global__ __launch_bounds__(256) void pack_w_kernel(const float* __restrict__ w,
                                                     ushort* __restrict__ wp) {
  int i = blockIdx.x * 256 + threadIdx.x;  // 294912
  int e = i & 7;
  int k8 = (i >> 3) & 3;
  int oc = (i >> 5) & 255;
  int cc = (i >> 13) & 1;
  int chalf = (i >> 14) & 1;
  int kk = i >> 15;  // 0..8
  int ch = chalf * 64 + cc * 32 + k8 * 8 + e;
  int kh = kk / 3, kw = kk - kh * 3;
  wp[i] = f2bf(w[((oc * CI + ch) * 3 + kh) * 3 + kw]);
}

// x [n][c][h][w] fp32 -> xn [n][chalf][h][w][64c] bf16.
// Coalesced reads (lane<->w), 16B-chunk XOR-swizzled LDS transpose, uint4 writes.
__global__ __launch_bounds__(256) void to_nhwc_kernel(const float* __restrict__ x,
                                                      ushort* __restrict__ xn) {
  __shared__ ushort lds[1792 * 8];  // 1792 16B chunks (112 w x 16 chunks), 28 KB
  int b = blockIdx.x;               // n*112 + h
  int n = b / HI;
  int h = b - n * HI;
  const float* xr = x + ((size_t)n * CI * HI) * WI + (size_t)h * WI;
  int t = threadIdx.x;
  int w = t & 127;   // active if < 112
  int cph = t >> 7;  // 0..1
  if (w < WI) {
    #pragma unroll
    for (int it = 0; it < 32; ++it) {
      int cp = it * 2 + cph;  // channel pair 0..63
      int c = cp * 2;
      float f0 = xr[(size_t)c * (HI * WI) + w];
      float f1 = xr[(size_t)(c + 1) * (HI * WI) + w];
      unsigned int pk = (unsigned int)f2bf(f0) | ((unsigned int)f2bf(f1) << 16);
      int chunk = w * 16 + ((cp >> 2) ^ (w & 15));
      *(unsigned int*)((char*)lds + chunk * 16 + (cp & 3) * 4) = pk;
    }
  }
  __syncthreads();
  #pragma unroll
  for (int it = 0; it < 7; ++it) {
    int j = it * 256 + t;  // chunk id: w = j>>4, c8 = j&15
    int w2 = j >> 4, c8 = j & 15;
    int src = w2 * 16 + (c8 ^ (w2 & 15));
    uint4 v = *(const uint4*)((const char*)lds + src * 16);
    int chalf = c8 >> 3, c8i = c8 & 7;
    *(uint4*)&xn[((((size_t)n * 2 + chalf) * HI + h) * WI + w2) * 64 + c8i * 8] = v;
  }
}

// Implicit GEMM, 16x16x32 MFMA. Block = 256 thr (4 waves = 4 oc quarters),
// one output row x 256 oc. K split in 2 chalf chunks of 64 ch; 43.5 KB LDS
// -> 2 blocks/CU co-resident (cross-block latency hiding at 2 waves/SIMD).
// A (weights) double-buffered in regs, prefetched one (tap,cc) ahead.
__global__ __launch_bounds__(256, 2) void conv_mfma_kernel(const ushort* __restrict__ xn,
                                                           const ushort* __restrict__ wp,
                                                           const float* __restrict__ bias,
                                                           float* __restrict__ out) {
  __shared__ ushort lds[340 * 64];  // 3 staged input rows (336 pix-rows of 128B) + pad
  const int bid = blockIdx.x;
  const int n = bid / HO;
  const int oh = bid - n * HO;
  const int t = threadIdx.x;
  const int lane = t & 63;
  const int wid = t >> 6;  // oc quarter
  const int lane15 = lane & 15;
  const int laneh = lane >> 4;  // 0..3
  const int oc0 = wid * 64;
  char* ldsb = (char*)lds;

  f32x4 acc[4][7] = {};  // [mf: oc 16-frag][nf: ow 16-frag]
  s16x8 abuf[2][4];      // A double-buffer (static indices after unroll)

  #pragma unroll
  for (int chalf = 0; chalf < 2; ++chalf) {
    if (chalf) __syncthreads();  // readers of previous chunk done
    // ---- stage 3 input rows of this chalf: async global->LDS, 43008 B ----
    const char* gsb = (const char*)(xn + (((size_t)n * 2 + chalf) * HI + oh) * (WI * 64));
    #pragma unroll
    for (int i = 0; i < 11; ++i) {
      int idx = i * 256 + t;
      if (idx < 2688) {
        int L = idx * 16;
        int go = L ^ (((L >> 7) & 7) << 4);  // pre-swizzled source, linear LDS dest
        __builtin_amdgcn_global_load_lds((gu32*)(gsb + go), (lu32*)(ldsb + L), 16, 0, 0);
      }
    }
    // prefetch first A of this chalf (drains with stage at the barrier)
    {
      const ushort* wb = wp + ((size_t)(chalf * 2)) * 8192 + (oc0 + lane15) * 32 + laneh * 8;
      #pragma unroll
      for (int mf = 0; mf < 4; ++mf) abuf[0][mf] = *(const s16x8*)(wb + mf * 512);
    }
    __syncthreads();

    // ---- 18 cc-steps: prefetch A(next) || load B || 28 MFMA ----
    #pragma unroll
    for (int sc = 0; sc < 18; ++sc) {
      const int kk = sc >> 1, cc = sc & 1;
      const int kh = kk / 3, kw = kk - kh * 3;
      if (sc < 17) {
        const int kk2 = (sc + 1) >> 1, cc2 = (sc + 1) & 1;
        const ushort* wb = wp + ((size_t)((kk2 * 2 + chalf) * 2 + cc2)) * 8192 +
                           (oc0 + lane15) * 32 + laneh * 8;
        #pragma unroll
        for (int mf = 0; mf < 4; ++mf) abuf[(sc + 1) & 1][mf] = *(const s16x8*)(wb + mf * 512);
      }
      s16x8 b[7];
      #pragma unroll
      for (int nf = 0; nf < 7; ++nf) {
        int R = kh * WI + nf * 16 + lane15 + kw;  // LDS pixel-row index
        int addr = (R << 7) + (((laneh * 16) ^ ((R & 7) << 4)) ^ (cc << 6));
        b[nf] = *(const s16x8*)(ldsb + addr);
      }
      #pragma unroll
      for (int mf = 0; mf < 4; ++mf)
        #pragma unroll
        for (int nf = 0; nf < 7; ++nf)
          acc[mf][nf] = __builtin_amdgcn_mfma_f32_16x16x32_bf16(abuf[sc & 1][mf], b[nf],
                                                                acc[mf][nf], 0, 0, 0);
    }
  }

  // ---- epilogue: D col=lane15 -> ow, row=laneh*4+r -> oc ----
  float* outb = out + ((size_t)n * OC) * (HO * WO) + (size_t)oh * WO;
  #pragma unroll
  for (int mf = 0; mf < 4; ++mf) {
    #pragma unroll
    for (int r = 0; r < 4; ++r) {
      const int oc = oc0 + mf * 16 + laneh * 4 + r;
      const float bv = bias[oc];
      float* op = outb + (size_t)oc * (HO * WO);
      #pragma unroll
      for (int nf = 0; nf < 7; ++nf) {
        int ow = nf * 16 + lane15;
        if (ow < WO) op[ow] = acc[mf][nf][r] + bv;
      }
    }
  }
}

// Correctness fallback if ws is too small for the packed bf16 buffers.
__global__ __launch_bounds__(256) void conv_naive_kernel(const float* __restrict__ x,
                                                         const float* __restrict__ w,
                                                         const float* __restrict__ bias,
                                                         float* __restrict__ out) {
  long i = (long)blockIdx.x * 256 + threadIdx.x;
  const long total = (long)NI * OC * HO * WO;
  if (i >= total) return;
  int ow = (int)(i % WO);
  long r1 = i / WO;
  int oh = (int)(r1 % HO);
  long r2 = r1 / HO;
  int oc = (int)(r2 % OC);
  int n = (int)(r2 / OC);
  float s = bias[oc];
  const float* xb = x + ((size_t)n * CI * HI) * WI;
  const float* wb = w + (size_t)oc * CI * 9;
  for (int c = 0; c < CI; ++c)
    for (int kh = 0; kh < 3; ++kh)
      for (int kw = 0; kw < 3; ++kw)
        s += xb[((size_t)c * HI + oh + kh) * WI + ow + kw] * wb[(c * 3 + kh) * 3 + kw];
  out[i] = s;
}

extern "C" void kernel_launch(void* const* d_in, const int* in_sizes, int n_in,
                              void* d_out, int out_size, void* d_ws, size_t ws_size,
                              hipStream_t stream) {
  const float* x = (const float*)d_in[0];
  const float* w = (const float*)d_in[1];
  const float* bias = (const float*)d_in[2];
  float* out = (float*)d_out;

  const size_t xn_elems = (size_t)NI * 2 * HI * WI * 64;  // 51,380,224
  const size_t wp_elems = (size_t)9 * 2 * 2 * 256 * 32;   // 294,912
  const size_t need = (xn_elems + wp_elems) * sizeof(ushort);

  if (ws_size >= need) {
    ushort* xnw = (ushort*)d_ws;
    ushort* wpw = xnw + xn_elems;
    hipLaunchKernelGGL(pack_w_kernel, dim3((unsigned)(wp_elems / 256)), dim3(256), 0, stream,
                       w, wpw);
    hipLaunchKernelGGL(to_nhwc_kernel, dim3(NI * HI), dim3(256), 0, stream, x, xnw);
    hipLaunchKernelGGL(conv_mfma_kernel, dim3(NI * HO), dim3(256), 0, stream, xnw, wpw, bias,
                       out);
  } else {
    long total = (long)NI * OC * HO * WO;
    hipLaunchKernelGGL(conv_naive_kernel, dim3((unsigned)((total + 255) / 256)), dim3(256), 0,
                       stream, x, w, bias, out);
  }
}

// Round 5
// 299.856 us; speedup vs baseline: 6.7059x; 1.2408x over previous
//
#include <hip/hip_runtime.h>

#define NI 32
#define CI 128
#define HI 112
#define WI 112
#define OC 256
#define HO 110
#define WO 110

typedef float f32x4 __attribute__((ext_vector_type(4)));
typedef short s16x8 __attribute__((ext_vector_type(8)));

typedef const unsigned int __attribute__((address_space(1))) gu32;
typedef unsigned int __attribute__((address_space(3))) lu32;

__device__ __forceinline__ ushort f2bf(float f) {
  union { float f; unsigned int u; } x; x.f = f;
  unsigned int r = x.u + 0x7FFFu + ((x.u >> 16) & 1u);
  return (ushort)(r >> 16);
}

// weight [oc][c][kh][kw] fp32 -> wp [kk][cq][oc][32ch] bf16  (cq = 32-ch quarter)
__global__ __launch_bounds__(256) void pack_w_kernel(const float* __restrict__ w,
                                                     ushort* __restrict__ wp) {
  int i = blockIdx.x * 256 + threadIdx.x;  // 294912
  int e = i & 7;
  int k8 = (i >> 3) & 3;
  int oc = (i >> 5) & 255;
  int cq = (i >> 13) & 3;
  int kk = i >> 15;  // 0..8
  int ch = cq * 32 + k8 * 8 + e;
  int kh = kk / 3, kw = kk - kh * 3;
  wp[i] = f2bf(w[((oc * CI + ch) * 3 + kh) * 3 + kw]);
}

// x [n][c][h][w] fp32 -> xn [n][cq][h][w][32c] bf16.
// Coalesced reads (lane<->w), 16B-chunk XOR-swizzled LDS transpose, uint4 writes.
__global__ __launch_bounds__(256) void to_nhwc_kernel(const float* __restrict__ x,
                                                      ushort* __restrict__ xn) {
  __shared__ ushort lds[1792 * 8];  // 1792 16B chunks (112 w x 16 chunks), 28 KB
  int b = blockIdx.x;               // n*112 + h
  int n = b / HI;
  int h = b - n * HI;
  const float* xr = x + ((size_t)n * CI * HI) * WI + (size_t)h * WI;
  int t = threadIdx.x;
  int w = t & 127;   // active if < 112
  int cph = t >> 7;  // 0..1
  if (w < WI) {
    #pragma unroll
    for (int it = 0; it < 32; ++it) {
      int cp = it * 2 + cph;  // channel pair 0..63
      int c = cp * 2;
      float f0 = xr[(size_t)c * (HI * WI) + w];
      float f1 = xr[(size_t)(c + 1) * (HI * WI) + w];
      unsigned int pk = (unsigned int)f2bf(f0) | ((unsigned int)f2bf(f1) << 16);
      int chunk = w * 16 + ((cp >> 2) ^ (w & 15));
      *(unsigned int*)((char*)lds + chunk * 16 + (cp & 3) * 4) = pk;
    }
  }
  __syncthreads();
  #pragma unroll
  for (int it = 0; it < 7; ++it) {
    int j = it * 256 + t;  // chunk id: w = j>>4, c8 = j&15
    int w2 = j >> 4, c8 = j & 15;
    int src = w2 * 16 + (c8 ^ (w2 & 15));
    uint4 v = *(const uint4*)((const char*)lds + src * 16);
    int cq = c8 >> 2, g = c8 & 3;
    *(uint4*)&xn[((((size_t)n * 4 + cq) * HI + h) * WI + w2) * 32 + g * 8] = v;
  }
}

// Implicit GEMM, 16x16x32 MFMA. Block = 256 thr (4 waves = 4 oc quarters),
// one output row x 256 oc. K = 4 quarters of 32 ch, double-buffered 21.75 KB
// LDS quarters staged via global_load_lds DURING compute (no serial stage
// phase); one barrier per quarter. 43.5 KB LDS -> 2 blocks/CU.
__global__ __launch_bounds__(256, 2) void conv_mfma_kernel(const ushort* __restrict__ xn,
                                                           const ushort* __restrict__ wp,
                                                           const float* __restrict__ bias,
                                                           float* __restrict__ out) {
  // 2 quarter buffers: 340 pixel-rows x 64 B (336 used + overread pad)
  __shared__ ushort lds[2 * 340 * 32];
  const int bid = blockIdx.x;
  // bijective XCD swizzle (3520 = 8*440): consecutive oh share an XCD's L2
  const int orig = (bid & 7) * 440 + (bid >> 3);
  const int n = orig / HO;
  const int oh = orig - n * HO;
  const int t = threadIdx.x;
  const int lane = t & 63;
  const int wid = t >> 6;  // oc quarter
  const int lane15 = lane & 15;
  const int laneh = lane >> 4;  // 0..3
  const int oc0 = wid * 64;
  char* ldsb = (char*)lds;

  f32x4 acc[4][7] = {};  // [mf: oc 16-frag][nf: ow 16-frag]
  s16x8 abuf[2][4];      // A double-buffer (static indices after unroll)

  // ---- prologue: stage quarter 0, prefetch A(g=0) ----
  {
    const char* gsb = (const char*)(xn + ((((size_t)n * 4 + 0) * HI + oh) * WI) * 32);
    #pragma unroll
    for (int i = 0; i < 6; ++i) {
      int idx = i * 256 + t;
      if (idx < 1344) {
        int L = idx * 16;
        int go = L ^ (((L >> 7) & 3) << 4);  // pre-swizzled source, linear LDS dest
        __builtin_amdgcn_global_load_lds((gu32*)(gsb + go), (lu32*)(ldsb + L), 16, 0, 0);
      }
    }
    const ushort* wb = wp + (oc0 + lane15) * 32 + laneh * 8;  // (kk=0,cq=0)
    #pragma unroll
    for (int mf = 0; mf < 4; ++mf) abuf[0][mf] = *(const s16x8*)(wb + mf * 512);
  }
  __syncthreads();

  #pragma unroll
  for (int q = 0; q < 4; ++q) {
    if (q) __syncthreads();  // prev-quarter readers done; stage(q) landed
    const int qb = (q & 1) * 21760;
    #pragma unroll
    for (int kk = 0; kk < 9; ++kk) {
      const int g = q * 9 + kk;
      const int kh = kk / 3, kw = kk - kh * 3;
      // prefetch A for g+1 (one step ahead)
      if (g + 1 < 36) {
        const int g2 = g + 1;
        const int q2 = g2 / 9, kk2 = g2 - q2 * 9;
        const ushort* wb = wp + ((size_t)(kk2 * 4 + q2)) * 8192 + (oc0 + lane15) * 32 +
                           laneh * 8;
        #pragma unroll
        for (int mf = 0; mf < 4; ++mf)
          abuf[g2 & 1][mf] = *(const s16x8*)(wb + mf * 512);
      }
      // issue next quarter's stage during kk==0 (after A-prefetch in vmcnt order)
      if (kk == 0 && q < 3) {
        const char* gsb =
            (const char*)(xn + ((((size_t)n * 4 + (q + 1)) * HI + oh) * WI) * 32);
        char* ldst = ldsb + (((q + 1) & 1) * 21760);
        #pragma unroll
        for (int i = 0; i < 6; ++i) {
          int idx = i * 256 + t;
          if (idx < 1344) {
            int L = idx * 16;
            int go = L ^ (((L >> 7) & 3) << 4);
            __builtin_amdgcn_global_load_lds((gu32*)(gsb + go), (lu32*)(ldst + L), 16, 0, 0);
          }
        }
      }
      // B fragments from swizzled LDS quarter
      s16x8 b[7];
      #pragma unroll
      for (int nf = 0; nf < 7; ++nf) {
        int R = kh * WI + nf * 16 + lane15 + kw;  // staged pixel-row index
        int addr = qb + (R << 6) + ((laneh ^ ((R >> 1) & 3)) << 4);
        b[nf] = *(const s16x8*)(ldsb + addr);
      }
      __builtin_amdgcn_s_setprio(1);
      #pragma unroll
      for (int mf = 0; mf < 4; ++mf)
        #pragma unroll
        for (int nf = 0; nf < 7; ++nf)
          acc[mf][nf] = __builtin_amdgcn_mfma_f32_16x16x32_bf16(abuf[g & 1][mf], b[nf],
                                                                acc[mf][nf], 0, 0, 0);
      __builtin_amdgcn_s_setprio(0);
    }
  }

  // ---- epilogue: D col=lane15 -> ow, row=laneh*4+r -> oc ----
  float* outb = out + ((size_t)n * OC) * (HO * WO) + (size_t)oh * WO;
  #pragma unroll
  for (int mf = 0; mf < 4; ++mf) {
    #pragma unroll
    for (int r = 0; r < 4; ++r) {
      const int oc = oc0 + mf * 16 + laneh * 4 + r;
      const float bv = bias[oc];
      float* op = outb + (size_t)oc * (HO * WO);
      #pragma unroll
      for (int nf = 0; nf < 7; ++nf) {
        int ow = nf * 16 + lane15;
        if (ow < WO) op[ow] = acc[mf][nf][r] + bv;
      }
    }
  }
}

// Correctness fallback if ws is too small for the packed bf16 buffers.
__global__ __launch_bounds__(256) void conv_naive_kernel(const float* __restrict__ x,
                                                         const float* __restrict__ w,
                                                         const float* __restrict__ bias,
                                                         float* __restrict__ out) {
  long i = (long)blockIdx.x * 256 + threadIdx.x;
  const long total = (long)NI * OC * HO * WO;
  if (i >= total) return;
  int ow = (int)(i % WO);
  long r1 = i / WO;
  int oh = (int)(r1 % HO);
  long r2 = r1 / HO;
  int oc = (int)(r2 % OC);
  int n = (int)(r2 / OC);
  float s = bias[oc];
  const float* xb = x + ((size_t)n * CI * HI) * WI;
  const float* wb = w + (size_t)oc * CI * 9;
  for (int c = 0; c < CI; ++c)
    for (int kh = 0; kh < 3; ++kh)
      for (int kw = 0; kw < 3; ++kw)
        s += xb[((size_t)c * HI + oh + kh) * WI + ow + kw] * wb[(c * 3 + kh) * 3 + kw];
  out[i] = s;
}

extern "C" void kernel_launch(void* const* d_in, const int* in_sizes, int n_in,
                              void* d_out, int out_size, void* d_ws, size_t ws_size,
                              hipStream_t stream) {
  const float* x = (const float*)d_in[0];
  const float* w = (const float*)d_in[1];
  const float* bias = (const float*)d_in[2];
  float* out = (float*)d_out;

  const size_t xn_elems = (size_t)NI * 4 * HI * WI * 32;  // 51,380,224
  const size_t wp_elems = (size_t)9 * 4 * 256 * 32;       // 294,912
  const size_t need = (xn_elems + wp_elems) * sizeof(ushort);

  if (ws_size >= need) {
    ushort* xnw = (ushort*)d_ws;
    ushort* wpw = xnw + xn_elems;
    hipLaunchKernelGGL(pack_w_kernel, dim3((unsigned)(wp_elems / 256)), dim3(256), 0, stream,
                       w, wpw);
    hipLaunchKernelGGL(to_nhwc_kernel, dim3(NI * HI), dim3(256), 0, stream, x, xnw);
    hipLaunchKernelGGL(conv_mfma_kernel, dim3(NI * HO), dim3(256), 0, stream, xnw, wpw, bias,
                       out);
  } else {
    long total = (long)NI * OC * HO * WO;
    hipLaunchKernelGGL(conv_naive_kernel, dim3((unsigned)((total + 255) / 256)), dim3(256), 0,
                       stream, x, w, bias, out);
  }
}